// Round 9
// baseline (475.276 us; speedup 1.0000x reference)
//
#include <hip/hip_runtime.h>

#define H_N   100000
#define E_N   200000
#define NI_N  1000000
#define LN_EPS 1e-5f

// Edge buckets: 64 edges each -> one MLP tile per bucket. 200000/64 = 3125 exactly.
#define NBUCK_E 3125
// Node buckets: 64 nodes each. ceil(100000/64) = 1563.
#define NBUCK_H 1563
#define SUBCAP_E 128       // per-XCD sub-bucket cap (mean 40, sigma ~6)
#define SUBCAP_H 192       // per-XCD sub-bucket cap (mean 80, sigma ~9)
#define CAP_E 512          // total per-bucket cap (mean 320, sigma ~18)
#define CAP_H 1024         // total per-bucket cap (mean 640, sigma ~25)
#define BCNT_PAD 16        // one counter per 64B line: kills same-line atomic RMW serialization

typedef __attribute__((ext_vector_type(8))) short bf16x8;
typedef __attribute__((ext_vector_type(4))) float floatx4;
typedef __attribute__((ext_vector_type(4))) int intx4;
typedef __attribute__((ext_vector_type(4))) unsigned uintx4;

__device__ inline unsigned short f2bf(float f) {
  unsigned u = __builtin_bit_cast(unsigned, f);
  u += 0x7fffu + ((u >> 16) & 1u);           // round-to-nearest-even
  return (unsigned short)(u >> 16);
}
__device__ inline float bf2f(unsigned short s) {
  unsigned u = ((unsigned)s) << 16;
  return __builtin_bit_cast(float, u);
}
__device__ inline unsigned get_xcc() {
  unsigned x;
  asm volatile("s_getreg_b32 %0, hwreg(HW_REG_XCC_ID)" : "=s"(x));
  return x & 7;
}

// ---------------------------------------------------------------------------
// Merged prep+bucket kernel: bucket binning blocks FIRST (atomic-latency-bound
// long pole starts immediately), then fp32->bf16 conversions (HBM-BW-bound)
// fill remaining CUs. bcnt must be zeroed before launch (hipMemsetAsync).
// Complementary bottlenecks overlap instead of serializing (~35us saved).
// ---------------------------------------------------------------------------
#define BUCKET_BLKS    977     // ceil(NI_N/4/256)
#define PREP_XH_BLKS   12500   // H_N*128/4/256
#define PREP_ATTR_BLKS 12500   // E_N*64/4/256
#define PREP_W1_BLKS   24      // 128*192/4/256
#define PREP_W_BLKS    16      // 128*128/4/256
#define PREP_TOTAL (BUCKET_BLKS + PREP_XH_BLKS + PREP_ATTR_BLKS + PREP_W1_BLKS + 4*PREP_W_BLKS)

__device__ inline void cvt4(const float4* __restrict__ src,
                            unsigned short* __restrict__ dst, int i, int n4) {
  if (i >= n4) return;
  float4 v = src[i];
  union { unsigned short us[4]; unsigned long long u64; } p;
  p.us[0] = f2bf(v.x); p.us[1] = f2bf(v.y);
  p.us[2] = f2bf(v.z); p.us[3] = f2bf(v.w);
  *(unsigned long long*)(dst + (size_t)i * 4) = p.u64;
}

__global__ __launch_bounds__(256) void k_prep_bucket(
    const int* __restrict__ fg, const int* __restrict__ res,
    int* __restrict__ bcnt_e, int* __restrict__ bcnt_h,
    unsigned* __restrict__ pairs_e, unsigned* __restrict__ pairs_h,
    const float4* __restrict__ x_h, unsigned short* __restrict__ xh_bf,
    const float4* __restrict__ attr, unsigned short* __restrict__ attr_bf,
    const float4* __restrict__ We1, unsigned short* __restrict__ w1,
    const float4* __restrict__ We2, unsigned short* __restrict__ w2,
    const float4* __restrict__ Wn1, unsigned short* __restrict__ wn1,
    const float4* __restrict__ Wn2, unsigned short* __restrict__ wn2,
    const float4* __restrict__ Wp, unsigned short* __restrict__ wp) {
  int blk = blockIdx.x;
  int tid = threadIdx.x;
  if (blk < BUCKET_BLKS) {
    int i0 = (blk * 256 + tid) * 4;
    if (i0 >= NI_N) return;
    unsigned xcc = get_xcc();
    intx4 f4 = __builtin_nontemporal_load((const intx4*)(fg + i0));
    intx4 r4 = __builtin_nontemporal_load((const intx4*)(res + i0));
#pragma unroll
    for (int j = 0; j < 4; ++j) {
      int f = f4[j], r = r4[j];
      int be = r >> 6, se = r & 63;
      int pe = atomicAdd(bcnt_e + ((size_t)xcc * NBUCK_E + be) * BCNT_PAD, 1);
      if (pe < SUBCAP_E)
        __builtin_nontemporal_store(((unsigned)se << 24) | (unsigned)f,
            &pairs_e[((size_t)xcc * NBUCK_E + be) * SUBCAP_E + pe]);
      int bh = f >> 6, sh = f & 63;
      int ph = atomicAdd(bcnt_h + ((size_t)xcc * NBUCK_H + bh) * BCNT_PAD, 1);
      if (ph < SUBCAP_H)
        __builtin_nontemporal_store(((unsigned)sh << 24) | (unsigned)r,
            &pairs_h[((size_t)xcc * NBUCK_H + bh) * SUBCAP_H + ph]);
    }
    return;
  }
  blk -= BUCKET_BLKS;
  if (blk < PREP_XH_BLKS) {
    cvt4(x_h, xh_bf, blk * 256 + tid, H_N * 128 / 4);
    return;
  }
  blk -= PREP_XH_BLKS;
  if (blk < PREP_ATTR_BLKS) {
    cvt4(attr, attr_bf, blk * 256 + tid, E_N * 64 / 4);
    return;
  }
  blk -= PREP_ATTR_BLKS;
  if (blk < PREP_W1_BLKS) {
    cvt4(We1, w1, blk * 256 + tid, 128 * 192 / 4);
    return;
  }
  blk -= PREP_W1_BLKS;
  if (blk < PREP_W_BLKS) {
    cvt4(We2, w2, blk * 256 + tid, 128 * 128 / 4);
    return;
  }
  blk -= PREP_W_BLKS;
  if (blk < PREP_W_BLKS) {
    cvt4(Wn1, wn1, blk * 256 + tid, 128 * 128 / 4);
    return;
  }
  blk -= PREP_W_BLKS;
  if (blk < PREP_W_BLKS) {
    cvt4(Wn2, wn2, blk * 256 + tid, 128 * 128 / 4);
    return;
  }
  blk -= PREP_W_BLKS;
  cvt4(Wp, wp, blk * 256 + tid, 128 * 128 / 4);
}

// ---------------------------------------------------------------------------
// Quarter-owned-segment gather: each 16-lane quarter (qid = t>>4, 0..15)
// owns segments qid, qid+16, qid+32, qid+48 and walks ALL their entries:
// one dwordx4 load covers the full 256B row (lane ql = 16B slice). Loads
// within a quarter are independent; 4 quarters run concurrently.
// NOTE (R8 post-mortem): three ILP structures all land at ~110-122us with
// constant FETCH_SIZE -> the gather is throughput-bound on the random-256B
// fetch path (~2.0-2.3 TB/s), not latency-bound. Do not re-engineer ILP.
// ---------------------------------------------------------------------------
#define GATHER_QSEG(basePtr)                                                   \
  {                                                                            \
    const int qid = (t >> 4);                                                  \
    for (int k = 0; k < 4; ++k) {                                              \
      int s = qid + 16 * k;                                                    \
      int o = cnts[s], e = cnts[s + 1];                                        \
      float a[8];                                                              \
      _Pragma("unroll")                                                        \
      for (int x = 0; x < 8; ++x) a[x] = 0.f;                                  \
      int j = o;                                                               \
      for (; j + 1 < e; j += 2) {                                              \
        unsigned off0 = sortedp[j], off1 = sortedp[j + 1];                     \
        uintx4 v0 = *(const uintx4*)((const char*)(basePtr) + off0 + ql * 16); \
        uintx4 v1 = *(const uintx4*)((const char*)(basePtr) + off1 + ql * 16); \
        _Pragma("unroll")                                                      \
        for (int x = 0; x < 4; ++x) {                                          \
          a[2 * x]     += bf2f((unsigned short)(v0[x] & 0xffffu)) +            \
                          bf2f((unsigned short)(v1[x] & 0xffffu));             \
          a[2 * x + 1] += bf2f((unsigned short)(v0[x] >> 16)) +                \
                          bf2f((unsigned short)(v1[x] >> 16));                 \
        }                                                                      \
      }                                                                        \
      if (j < e) {                                                             \
        unsigned off0 = sortedp[j];                                            \
        uintx4 v0 = *(const uintx4*)((const char*)(basePtr) + off0 + ql * 16); \
        _Pragma("unroll")                                                      \
        for (int x = 0; x < 4; ++x) {                                          \
          a[2 * x]     += bf2f((unsigned short)(v0[x] & 0xffffu));             \
          a[2 * x + 1] += bf2f((unsigned short)(v0[x] >> 16));                 \
        }                                                                      \
      }                                                                        \
      float inv = (e > o) ? 1.0f / (float)(e - o) : 0.0f;                      \
      uintx4 ov;                                                               \
      _Pragma("unroll")                                                        \
      for (int x = 0; x < 4; ++x)                                              \
        ov[x] = (unsigned)f2bf(a[2 * x] * inv) |                               \
                ((unsigned)f2bf(a[2 * x + 1] * inv) << 16);                    \
      *(uintx4*)&meanS[s][ql * 8] = ov;                                        \
    }                                                                          \
  }

// ---------------------------------------------------------------------------
// Fused edge: concat -> counting sort -> quarter-owned-segment gather-mean
// -> edge MLP. h1 overlays meanS (barrier-separated). LDS ~22KB, 6 blk/CU.
// ---------------------------------------------------------------------------
__global__ __launch_bounds__(256, 6) void k_edge_fused(
    const unsigned short* __restrict__ xh, const short* __restrict__ attr_bf,
    const unsigned* __restrict__ pairs, const int* __restrict__ bcnt,
    const short* __restrict__ w1, const float* __restrict__ b1,
    const short* __restrict__ w2, const float* __restrict__ b2,
    unsigned short* __restrict__ edge_msg) {
  __shared__ short meanS[64][136];     // 17408 B; doubles as h1 after barrier
  __shared__ unsigned raw[CAP_E];      // 2048
  __shared__ unsigned sortedp[CAP_E];  // 2048
  __shared__ int cnts[65];
  __shared__ int curs[64];
  short (*h1s)[136] = meanS;

  const int b = blockIdx.x;
  const int t = threadIdx.x;

  // ---- concat 8 per-XCD sub-lists ----
  int total = 0;
#pragma unroll
  for (int x = 0; x < 8; ++x) {
    int c = min(bcnt[((size_t)x * NBUCK_E + b) * BCNT_PAD], SUBCAP_E);
    const unsigned* src = pairs + ((size_t)x * NBUCK_E + b) * SUBCAP_E;
    for (int j = t; j < c; j += 256) {
      int d = total + j;
      if (d < CAP_E) raw[d] = src[j];
    }
    total += c;
  }
  const int cnt = min(total, CAP_E);
  if (t <= 64) cnts[t] = 0;
  __syncthreads();
  for (int j = t; j < cnt; j += 256)
    atomicAdd(&cnts[(raw[j] >> 24) + 1], 1);
  __syncthreads();
  for (int d = 1; d <= 64; d <<= 1) {
    int v = 0;
    if (t <= 64 && t >= d) v = cnts[t - d];
    __syncthreads();
    if (t <= 64) cnts[t] += v;
    __syncthreads();
  }
  if (t < 64) curs[t] = cnts[t];
  __syncthreads();
  for (int j = t; j < cnt; j += 256) {
    unsigned p = raw[j];
    int d = atomicAdd(&curs[p >> 24], 1);
    sortedp[d] = (p & 0xFFFFFFu) << 8;   // byte offset of 256B row
  }
  __syncthreads();

  // ---- quarter-owned-segment gather-mean into LDS tile ----
  const int wave = t >> 6, lane = t & 63;
  const int ql = lane & 15;
  GATHER_QSEG(xh);
  __syncthreads();

  // ---- edge MLP (A from LDS) ----
  const int row  = lane & 15;
  const int quad = lane >> 4;
  const int e0   = b * 64;
  const int cb   = wave * 32;

  bf16x8 B1[2][6];
#pragma unroll
  for (int nl = 0; nl < 2; ++nl)
#pragma unroll
    for (int ks = 0; ks < 6; ++ks)
      B1[nl][ks] = *(const bf16x8*)(w1 + (size_t)(cb + nl * 16 + row) * 192 +
                                    ks * 32 + quad * 8);

  floatx4 acc[4][2];
#pragma unroll
  for (int m = 0; m < 4; ++m)
#pragma unroll
    for (int nl = 0; nl < 2; ++nl) acc[m][nl] = (floatx4){0.f, 0.f, 0.f, 0.f};

#pragma unroll
  for (int ks = 0; ks < 6; ++ks) {
    bf16x8 a[4];
#pragma unroll
    for (int m = 0; m < 4; ++m) {
      if (ks < 4) {
        a[m] = *(const bf16x8*)&meanS[m * 16 + row][ks * 32 + quad * 8];
      } else {
        int e = e0 + m * 16 + row;
        a[m] = *(const bf16x8*)(attr_bf + (size_t)e * 64 + (ks - 4) * 32 + quad * 8);
      }
    }
#pragma unroll
    for (int m = 0; m < 4; ++m)
#pragma unroll
      for (int nl = 0; nl < 2; ++nl)
        acc[m][nl] = __builtin_amdgcn_mfma_f32_16x16x32_bf16(a[m], B1[nl][ks],
                                                             acc[m][nl], 0, 0, 0);
  }
  __syncthreads();   // all meanS reads done before h1 overlay writes

#pragma unroll
  for (int nl = 0; nl < 2; ++nl) {
    float bias = b1[cb + nl * 16 + row];
#pragma unroll
    for (int m = 0; m < 4; ++m)
#pragma unroll
      for (int r = 0; r < 4; ++r)
        h1s[m * 16 + quad * 4 + r][cb + nl * 16 + row] =
            (short)f2bf(fmaxf(acc[m][nl][r] + bias, 0.0f));
  }

  bf16x8 B2[2][4];
#pragma unroll
  for (int nl = 0; nl < 2; ++nl)
#pragma unroll
    for (int ks = 0; ks < 4; ++ks)
      B2[nl][ks] = *(const bf16x8*)(w2 + (size_t)(cb + nl * 16 + row) * 128 +
                                    ks * 32 + quad * 8);
  __syncthreads();

  floatx4 acc2[4][2];
#pragma unroll
  for (int m = 0; m < 4; ++m)
#pragma unroll
    for (int nl = 0; nl < 2; ++nl) acc2[m][nl] = (floatx4){0.f, 0.f, 0.f, 0.f};

#pragma unroll
  for (int ks = 0; ks < 4; ++ks) {
    bf16x8 a[4];
#pragma unroll
    for (int m = 0; m < 4; ++m)
      a[m] = *(const bf16x8*)&h1s[m * 16 + row][ks * 32 + quad * 8];
#pragma unroll
    for (int m = 0; m < 4; ++m)
#pragma unroll
      for (int nl = 0; nl < 2; ++nl)
        acc2[m][nl] = __builtin_amdgcn_mfma_f32_16x16x32_bf16(a[m], B2[nl][ks],
                                                              acc2[m][nl], 0, 0, 0);
  }

#pragma unroll
  for (int nl = 0; nl < 2; ++nl) {
    int col = cb + nl * 16 + row;
    float bias = b2[col];
#pragma unroll
    for (int m = 0; m < 4; ++m)
#pragma unroll
      for (int r = 0; r < 4; ++r)
        edge_msg[(size_t)(e0 + m * 16 + quad * 4 + r) * 128 + col] =
            f2bf(acc2[m][nl][r] + bias);
  }
}

// ---------------------------------------------------------------------------
// Fused node: quarter-owned-segment gather on edge_msg rows + node MLP + LN.
// LDS ~26.1KB -> 5 blocks/CU: h1 overlays meanS, part overlays raw.
// ---------------------------------------------------------------------------
__global__ __launch_bounds__(256, 5) void k_node_fused(
    const unsigned short* __restrict__ emsg, const short* __restrict__ xh_bf,
    const unsigned* __restrict__ pairs, const int* __restrict__ bcnt,
    const short* __restrict__ wp, const float* __restrict__ bp,
    const short* __restrict__ wn1, const float* __restrict__ bn1,
    const short* __restrict__ wn2, const float* __restrict__ bn2,
    const float* __restrict__ gamma, const float* __restrict__ beta,
    float* __restrict__ out) {
  __shared__ short meanS[64][136];     // 17408 B; doubles as h1
  __shared__ unsigned raw[CAP_H];      // 4096 B; doubles as part[64][4] (2048 B)
  __shared__ unsigned sortedp[CAP_H];  // 4096
  __shared__ int cnts[65];
  __shared__ int curs[64];
  short (*h1s)[136] = meanS;
  float2 (*part)[4] = (float2(*)[4])raw;

  const int b = blockIdx.x;
  const int t = threadIdx.x;

  int total = 0;
#pragma unroll
  for (int x = 0; x < 8; ++x) {
    int c = min(bcnt[((size_t)x * NBUCK_H + b) * BCNT_PAD], SUBCAP_H);
    const unsigned* src = pairs + ((size_t)x * NBUCK_H + b) * SUBCAP_H;
    for (int j = t; j < c; j += 256) {
      int d = total + j;
      if (d < CAP_H) raw[d] = src[j];
    }
    total += c;
  }
  const int cnt = min(total, CAP_H);
  if (t <= 64) cnts[t] = 0;
  __syncthreads();
  for (int j = t; j < cnt; j += 256)
    atomicAdd(&cnts[(raw[j] >> 24) + 1], 1);
  __syncthreads();
  for (int d = 1; d <= 64; d <<= 1) {
    int v = 0;
    if (t <= 64 && t >= d) v = cnts[t - d];
    __syncthreads();
    if (t <= 64) cnts[t] += v;
    __syncthreads();
  }
  if (t < 64) curs[t] = cnts[t];
  __syncthreads();
  for (int j = t; j < cnt; j += 256) {
    unsigned p = raw[j];
    int d = atomicAdd(&curs[p >> 24], 1);
    sortedp[d] = (p & 0xFFFFFFu) << 8;   // byte offset of 256B row
  }
  __syncthreads();

  const int wave = t >> 6, lane = t & 63;
  const int ql = lane & 15;
  GATHER_QSEG(emsg);
  __syncthreads();

  // ---- node MLP + LN (A from LDS) ----
  const int row  = lane & 15;
  const int quad = lane >> 4;
  const int n0   = b * 64;
  const int cb   = wave * 32;

  bf16x8 B1[2][4];
#pragma unroll
  for (int nl = 0; nl < 2; ++nl)
#pragma unroll
    for (int ks = 0; ks < 4; ++ks)
      B1[nl][ks] = *(const bf16x8*)(wn1 + (size_t)(cb + nl * 16 + row) * 128 +
                                    ks * 32 + quad * 8);

  floatx4 acc[4][2];
#pragma unroll
  for (int m = 0; m < 4; ++m)
#pragma unroll
    for (int nl = 0; nl < 2; ++nl) acc[m][nl] = (floatx4){0.f, 0.f, 0.f, 0.f};

#pragma unroll
  for (int ks = 0; ks < 4; ++ks) {
    bf16x8 a[4];
#pragma unroll
    for (int m = 0; m < 4; ++m)
      a[m] = *(const bf16x8*)&meanS[m * 16 + row][ks * 32 + quad * 8];
#pragma unroll
    for (int m = 0; m < 4; ++m)
#pragma unroll
      for (int nl = 0; nl < 2; ++nl)
        acc[m][nl] = __builtin_amdgcn_mfma_f32_16x16x32_bf16(a[m], B1[nl][ks],
                                                             acc[m][nl], 0, 0, 0);
  }
  __syncthreads();   // all meanS reads done before h1 overlay writes

#pragma unroll
  for (int nl = 0; nl < 2; ++nl) {
    float bias = bn1[cb + nl * 16 + row];
#pragma unroll
    for (int m = 0; m < 4; ++m)
#pragma unroll
      for (int r = 0; r < 4; ++r)
        h1s[m * 16 + quad * 4 + r][cb + nl * 16 + row] =
            (short)f2bf(fmaxf(acc[m][nl][r] + bias, 0.0f));
  }

  bf16x8 B2[2][4], Bp[2][4];
#pragma unroll
  for (int nl = 0; nl < 2; ++nl)
#pragma unroll
    for (int ks = 0; ks < 4; ++ks) {
      B2[nl][ks] = *(const bf16x8*)(wn2 + (size_t)(cb + nl * 16 + row) * 128 +
                                    ks * 32 + quad * 8);
      Bp[nl][ks] = *(const bf16x8*)(wp + (size_t)(cb + nl * 16 + row) * 128 +
                                    ks * 32 + quad * 8);
    }
  __syncthreads();

  floatx4 acc2[4][2];
#pragma unroll
  for (int m = 0; m < 4; ++m)
#pragma unroll
    for (int nl = 0; nl < 2; ++nl) acc2[m][nl] = (floatx4){0.f, 0.f, 0.f, 0.f};

#pragma unroll
  for (int ks = 0; ks < 4; ++ks) {
    bf16x8 at[4], ax[4];
#pragma unroll
    for (int m = 0; m < 4; ++m) {
      at[m] = *(const bf16x8*)&h1s[m * 16 + row][ks * 32 + quad * 8];
      int n = n0 + m * 16 + row;
      ax[m] = *(const bf16x8*)(xh_bf + (size_t)n * 128 + ks * 32 + quad * 8);
    }
#pragma unroll
    for (int m = 0; m < 4; ++m)
#pragma unroll
      for (int nl = 0; nl < 2; ++nl) {
        acc2[m][nl] = __builtin_amdgcn_mfma_f32_16x16x32_bf16(at[m], B2[nl][ks],
                                                              acc2[m][nl], 0, 0, 0);
        acc2[m][nl] = __builtin_amdgcn_mfma_f32_16x16x32_bf16(ax[m], Bp[nl][ks],
                                                              acc2[m][nl], 0, 0, 0);
      }
  }

  float z[4][2][4];
#pragma unroll
  for (int m = 0; m < 4; ++m) {
    float s[4], ss[4];
#pragma unroll
    for (int r = 0; r < 4; ++r) { s[r] = 0.f; ss[r] = 0.f; }
#pragma unroll
    for (int nl = 0; nl < 2; ++nl) {
      float bias = bp[cb + nl * 16 + row] + bn2[cb + nl * 16 + row];
#pragma unroll
      for (int r = 0; r < 4; ++r) {
        float v = fmaxf(acc2[m][nl][r] + bias, 0.0f);
        z[m][nl][r] = v;
        s[r] += v;
        ss[r] += v * v;
      }
    }
#pragma unroll
    for (int r = 0; r < 4; ++r) {
#pragma unroll
      for (int msk = 1; msk < 16; msk <<= 1) {
        s[r]  += __shfl_xor(s[r],  msk, 64);
        ss[r] += __shfl_xor(ss[r], msk, 64);
      }
      if (row == 0) part[m * 16 + quad * 4 + r][wave] = make_float2(s[r], ss[r]);
    }
  }
  __syncthreads();

#pragma unroll
  for (int m = 0; m < 4; ++m)
#pragma unroll
    for (int r = 0; r < 4; ++r) {
      int rr = m * 16 + quad * 4 + r;
      float2 p0 = part[rr][0], p1 = part[rr][1], p2 = part[rr][2], p3 = part[rr][3];
      float mean = (p0.x + p1.x + p2.x + p3.x) * (1.0f / 128.0f);
      float var  = (p0.y + p1.y + p2.y + p3.y) * (1.0f / 128.0f) - mean * mean;
      float rstd = rsqrtf(var + LN_EPS);
      int n = n0 + rr;
      if (n < H_N) {
#pragma unroll
        for (int nl = 0; nl < 2; ++nl) {
          int col = cb + nl * 16 + row;
          out[(size_t)n * 128 + col] =
              (z[m][nl][r] - mean) * rstd * gamma[col] + beta[col];
        }
      }
    }
}

// ---------------------------------------------------------------------------
extern "C" void kernel_launch(void* const* d_in, const int* in_sizes, int n_in,
                              void* d_out, int out_size, void* d_ws, size_t ws_size,
                              hipStream_t stream) {
  const float* x_h   = (const float*)d_in[0];
  const float* attr  = (const float*)d_in[1];
  const float* Wp    = (const float*)d_in[2];
  const float* bp    = (const float*)d_in[3];
  const float* We1   = (const float*)d_in[4];
  const float* be1   = (const float*)d_in[5];
  const float* We2   = (const float*)d_in[6];
  const float* be2   = (const float*)d_in[7];
  const float* Wn1   = (const float*)d_in[8];
  const float* bn1   = (const float*)d_in[9];
  const float* Wn2   = (const float*)d_in[10];
  const float* bn2   = (const float*)d_in[11];
  const float* gamma = (const float*)d_in[12];
  const float* beta  = (const float*)d_in[13];
  const int*   fg    = (const int*)d_in[14];
  const int*   res   = (const int*)d_in[15];
  float* out = (float*)d_out;

  // ---- workspace layout ----
  int* bcnt_e = (int*)d_ws;                                  // 8*NBUCK_E*16
  int* bcnt_h = bcnt_e + (size_t)8 * NBUCK_E * BCNT_PAD;     // 8*NBUCK_H*16
  unsigned* pairs_e = (unsigned*)(bcnt_h + (size_t)8 * NBUCK_H * BCNT_PAD);
  unsigned* pairs_h = pairs_e + (size_t)8 * NBUCK_E * SUBCAP_E;
  unsigned short* xh_bf    = (unsigned short*)(pairs_h + (size_t)8 * NBUCK_H * SUBCAP_H);
  unsigned short* edge_msg = xh_bf + (size_t)H_N * 128;
  short* w1  = (short*)(edge_msg + (size_t)E_N * 128);
  short* w2  = w1 + 128 * 192;
  short* wn1 = w2 + 128 * 128;
  short* wn2 = wn1 + 128 * 128;
  short* wp  = wn2 + 128 * 128;
  short* attr_bf = wp + 128 * 128;                           // E_N*64 bf16

  hipMemsetAsync(bcnt_e, 0,
                 (size_t)(8 * NBUCK_E + 8 * NBUCK_H) * BCNT_PAD * 4, stream);

  k_prep_bucket<<<PREP_TOTAL, 256, 0, stream>>>(
      fg, res, bcnt_e, bcnt_h, pairs_e, pairs_h,
      (const float4*)x_h, xh_bf,
      (const float4*)attr, (unsigned short*)attr_bf,
      (const float4*)We1, (unsigned short*)w1,
      (const float4*)We2, (unsigned short*)w2,
      (const float4*)Wn1, (unsigned short*)wn1,
      (const float4*)Wn2, (unsigned short*)wn2,
      (const float4*)Wp, (unsigned short*)wp);

  k_edge_fused<<<NBUCK_E, 256, 0, stream>>>(xh_bf, attr_bf, pairs_e, bcnt_e,
                                            w1, be1, w2, be2, edge_msg);
  k_node_fused<<<NBUCK_H, 256, 0, stream>>>(edge_msg, (const short*)xh_bf,
                                            pairs_h, bcnt_h,
                                            wp, bp, wn1, bn1, wn2, bn2,
                                            gamma, beta, out);
}

// Round 10
// 467.662 us; speedup vs baseline: 1.0163x; 1.0163x over previous
//
#include <hip/hip_runtime.h>

#define H_N   100000
#define E_N   200000
#define NI_N  1000000
#define LN_EPS 1e-5f

// Edge buckets: 64 edges each -> one MLP tile per bucket. 200000/64 = 3125 exactly.
#define NBUCK_E 3125
// Node buckets: 64 nodes each. ceil(100000/64) = 1563.
#define NBUCK_H 1563
#define SUBCAP_E 128       // per-XCD sub-bucket cap (mean 40, sigma ~6)
#define SUBCAP_H 192       // per-XCD sub-bucket cap (mean 80, sigma ~9)
#define CAP_E 512          // total per-bucket cap (mean 320, sigma ~18)
#define CAP_H 1024         // total per-bucket cap (mean 640, sigma ~25)
#define BCNT_PAD 16        // one counter per 64B line: kills same-line atomic RMW serialization

typedef __attribute__((ext_vector_type(8))) short bf16x8;
typedef __attribute__((ext_vector_type(4))) float floatx4;
typedef __attribute__((ext_vector_type(4))) int intx4;
typedef __attribute__((ext_vector_type(4))) unsigned uintx4;

__device__ inline unsigned short f2bf(float f) {
  unsigned u = __builtin_bit_cast(unsigned, f);
  u += 0x7fffu + ((u >> 16) & 1u);           // round-to-nearest-even
  return (unsigned short)(u >> 16);
}
__device__ inline float bf2f(unsigned short s) {
  unsigned u = ((unsigned)s) << 16;
  return __builtin_bit_cast(float, u);
}
__device__ inline unsigned get_xcc() {
  unsigned x;
  asm volatile("s_getreg_b32 %0, hwreg(HW_REG_XCC_ID)" : "=s"(x));
  return x & 7;
}

// ---------------------------------------------------------------------------
// Prep kernel: one launch does all fp32->bf16 conversions + bcnt zeroing.
// (R9 lesson: do NOT merge with k_bucket — cvt streaming traffic contends
// with bucket's atomic RMW path in TCC; merged ran 170us vs ~120us serial.)
// ---------------------------------------------------------------------------
#define PREP_XH_BLKS   12500   // H_N*128/4/256
#define PREP_ATTR_BLKS 12500   // E_N*64/4/256
#define PREP_W1_BLKS   24      // 128*192/4/256
#define PREP_W_BLKS    16      // 128*128/4/256
#define PREP_ZERO_BLKS 586     // (8*NBUCK_E+8*NBUCK_H)*BCNT_PAD/4/256
#define PREP_TOTAL (PREP_XH_BLKS + PREP_ATTR_BLKS + PREP_W1_BLKS + 4*PREP_W_BLKS + PREP_ZERO_BLKS)

__device__ inline void cvt4(const float4* __restrict__ src,
                            unsigned short* __restrict__ dst, int i, int n4) {
  if (i >= n4) return;
  float4 v = src[i];
  union { unsigned short us[4]; unsigned long long u64; } p;
  p.us[0] = f2bf(v.x); p.us[1] = f2bf(v.y);
  p.us[2] = f2bf(v.z); p.us[3] = f2bf(v.w);
  *(unsigned long long*)(dst + (size_t)i * 4) = p.u64;
}

__global__ __launch_bounds__(256) void k_prep(
    const float4* __restrict__ x_h, unsigned short* __restrict__ xh_bf,
    const float4* __restrict__ attr, unsigned short* __restrict__ attr_bf,
    const float4* __restrict__ We1, unsigned short* __restrict__ w1,
    const float4* __restrict__ We2, unsigned short* __restrict__ w2,
    const float4* __restrict__ Wn1, unsigned short* __restrict__ wn1,
    const float4* __restrict__ Wn2, unsigned short* __restrict__ wn2,
    const float4* __restrict__ Wp, unsigned short* __restrict__ wp,
    intx4* __restrict__ bcnt_zero) {
  int blk = blockIdx.x;
  int tid = threadIdx.x;
  if (blk < PREP_XH_BLKS) {
    cvt4(x_h, xh_bf, blk * 256 + tid, H_N * 128 / 4);
    return;
  }
  blk -= PREP_XH_BLKS;
  if (blk < PREP_ATTR_BLKS) {
    cvt4(attr, attr_bf, blk * 256 + tid, E_N * 64 / 4);
    return;
  }
  blk -= PREP_ATTR_BLKS;
  if (blk < PREP_W1_BLKS) {
    cvt4(We1, w1, blk * 256 + tid, 128 * 192 / 4);
    return;
  }
  blk -= PREP_W1_BLKS;
  if (blk < PREP_W_BLKS) {
    cvt4(We2, w2, blk * 256 + tid, 128 * 128 / 4);
    return;
  }
  blk -= PREP_W_BLKS;
  if (blk < PREP_W_BLKS) {
    cvt4(Wn1, wn1, blk * 256 + tid, 128 * 128 / 4);
    return;
  }
  blk -= PREP_W_BLKS;
  if (blk < PREP_W_BLKS) {
    cvt4(Wn2, wn2, blk * 256 + tid, 128 * 128 / 4);
    return;
  }
  blk -= PREP_W_BLKS;
  if (blk < PREP_W_BLKS) {
    cvt4(Wp, wp, blk * 256 + tid, 128 * 128 / 4);
    return;
  }
  blk -= PREP_W_BLKS;
  {
    int i = blk * 256 + tid;
    int n = (8 * NBUCK_E + 8 * NBUCK_H) * BCNT_PAD / 4;
    if (i < n) bcnt_zero[i] = (intx4){0, 0, 0, 0};
  }
}

// ---------------------------------------------------------------------------
// Bucket binning, XCD-local, 4 incidences/thread. Explicit atomic ILP:
// issue ALL 8 atomicAdds before any dependent store, so the 8 round-trips
// (~200-400cy each) overlap under in-order vmcnt instead of serializing.
// ---------------------------------------------------------------------------
__global__ __launch_bounds__(256) void k_bucket(
    const int* __restrict__ fg, const int* __restrict__ res,
    int* __restrict__ bcnt_e, int* __restrict__ bcnt_h,
    unsigned* __restrict__ pairs_e, unsigned* __restrict__ pairs_h) {
  int i0 = (blockIdx.x * 256 + threadIdx.x) * 4;
  if (i0 >= NI_N) return;
  unsigned xcc = get_xcc();
  intx4 f4 = __builtin_nontemporal_load((const intx4*)(fg + i0));
  intx4 r4 = __builtin_nontemporal_load((const intx4*)(res + i0));
  int pe[4], ph[4];
#pragma unroll
  for (int j = 0; j < 4; ++j) {
    pe[j] = atomicAdd(bcnt_e + ((size_t)xcc * NBUCK_E + (r4[j] >> 6)) * BCNT_PAD, 1);
    ph[j] = atomicAdd(bcnt_h + ((size_t)xcc * NBUCK_H + (f4[j] >> 6)) * BCNT_PAD, 1);
  }
#pragma unroll
  for (int j = 0; j < 4; ++j) {
    int f = f4[j], r = r4[j];
    if (pe[j] < SUBCAP_E)
      __builtin_nontemporal_store(((unsigned)(r & 63) << 24) | (unsigned)f,
          &pairs_e[((size_t)xcc * NBUCK_E + (r >> 6)) * SUBCAP_E + pe[j]]);
    if (ph[j] < SUBCAP_H)
      __builtin_nontemporal_store(((unsigned)(f & 63) << 24) | (unsigned)r,
          &pairs_h[((size_t)xcc * NBUCK_H + (f >> 6)) * SUBCAP_H + ph[j]]);
  }
}

// ---------------------------------------------------------------------------
// Quarter-owned-segment gather: each 16-lane quarter (qid = t>>4, 0..15)
// owns segments qid, qid+16, qid+32, qid+48 and walks ALL their entries:
// one dwordx4 load covers the full 256B row (lane ql = 16B slice). Loads
// within a quarter are independent; 4 quarters run concurrently.
// NOTE (R8 post-mortem): three ILP structures all land at ~110-122us with
// constant FETCH_SIZE -> the gather is throughput-bound on the random-256B
// fetch path (~2.0-2.3 TB/s), not latency-bound. Do not re-engineer ILP.
// ---------------------------------------------------------------------------
#define GATHER_QSEG(basePtr)                                                   \
  {                                                                            \
    const int qid = (t >> 4);                                                  \
    for (int k = 0; k < 4; ++k) {                                              \
      int s = qid + 16 * k;                                                    \
      int o = cnts[s], e = cnts[s + 1];                                        \
      float a[8];                                                              \
      _Pragma("unroll")                                                        \
      for (int x = 0; x < 8; ++x) a[x] = 0.f;                                  \
      int j = o;                                                               \
      for (; j + 1 < e; j += 2) {                                              \
        unsigned off0 = sortedp[j], off1 = sortedp[j + 1];                     \
        uintx4 v0 = *(const uintx4*)((const char*)(basePtr) + off0 + ql * 16); \
        uintx4 v1 = *(const uintx4*)((const char*)(basePtr) + off1 + ql * 16); \
        _Pragma("unroll")                                                      \
        for (int x = 0; x < 4; ++x) {                                          \
          a[2 * x]     += bf2f((unsigned short)(v0[x] & 0xffffu)) +            \
                          bf2f((unsigned short)(v1[x] & 0xffffu));             \
          a[2 * x + 1] += bf2f((unsigned short)(v0[x] >> 16)) +                \
                          bf2f((unsigned short)(v1[x] >> 16));                 \
        }                                                                      \
      }                                                                        \
      if (j < e) {                                                             \
        unsigned off0 = sortedp[j];                                            \
        uintx4 v0 = *(const uintx4*)((const char*)(basePtr) + off0 + ql * 16); \
        _Pragma("unroll")                                                      \
        for (int x = 0; x < 4; ++x) {                                          \
          a[2 * x]     += bf2f((unsigned short)(v0[x] & 0xffffu));             \
          a[2 * x + 1] += bf2f((unsigned short)(v0[x] >> 16));                 \
        }                                                                      \
      }                                                                        \
      float inv = (e > o) ? 1.0f / (float)(e - o) : 0.0f;                      \
      uintx4 ov;                                                               \
      _Pragma("unroll")                                                        \
      for (int x = 0; x < 4; ++x)                                              \
        ov[x] = (unsigned)f2bf(a[2 * x] * inv) |                               \
                ((unsigned)f2bf(a[2 * x + 1] * inv) << 16);                    \
      *(uintx4*)&meanS[s][ql * 8] = ov;                                        \
    }                                                                          \
  }

// ---------------------------------------------------------------------------
// Fused edge: concat -> counting sort -> quarter-owned-segment gather-mean
// -> edge MLP. h1 overlays meanS (barrier-separated). LDS ~22KB, 6 blk/CU.
// ---------------------------------------------------------------------------
__global__ __launch_bounds__(256, 6) void k_edge_fused(
    const unsigned short* __restrict__ xh, const short* __restrict__ attr_bf,
    const unsigned* __restrict__ pairs, const int* __restrict__ bcnt,
    const short* __restrict__ w1, const float* __restrict__ b1,
    const short* __restrict__ w2, const float* __restrict__ b2,
    unsigned short* __restrict__ edge_msg) {
  __shared__ short meanS[64][136];     // 17408 B; doubles as h1 after barrier
  __shared__ unsigned raw[CAP_E];      // 2048
  __shared__ unsigned sortedp[CAP_E];  // 2048
  __shared__ int cnts[65];
  __shared__ int curs[64];
  short (*h1s)[136] = meanS;

  const int b = blockIdx.x;
  const int t = threadIdx.x;

  // ---- concat 8 per-XCD sub-lists ----
  int total = 0;
#pragma unroll
  for (int x = 0; x < 8; ++x) {
    int c = min(bcnt[((size_t)x * NBUCK_E + b) * BCNT_PAD], SUBCAP_E);
    const unsigned* src = pairs + ((size_t)x * NBUCK_E + b) * SUBCAP_E;
    for (int j = t; j < c; j += 256) {
      int d = total + j;
      if (d < CAP_E) raw[d] = src[j];
    }
    total += c;
  }
  const int cnt = min(total, CAP_E);
  if (t <= 64) cnts[t] = 0;
  __syncthreads();
  for (int j = t; j < cnt; j += 256)
    atomicAdd(&cnts[(raw[j] >> 24) + 1], 1);
  __syncthreads();
  for (int d = 1; d <= 64; d <<= 1) {
    int v = 0;
    if (t <= 64 && t >= d) v = cnts[t - d];
    __syncthreads();
    if (t <= 64) cnts[t] += v;
    __syncthreads();
  }
  if (t < 64) curs[t] = cnts[t];
  __syncthreads();
  for (int j = t; j < cnt; j += 256) {
    unsigned p = raw[j];
    int d = atomicAdd(&curs[p >> 24], 1);
    sortedp[d] = (p & 0xFFFFFFu) << 8;   // byte offset of 256B row
  }
  __syncthreads();

  // ---- quarter-owned-segment gather-mean into LDS tile ----
  const int wave = t >> 6, lane = t & 63;
  const int ql = lane & 15;
  GATHER_QSEG(xh);
  __syncthreads();

  // ---- edge MLP (A from LDS) ----
  const int row  = lane & 15;
  const int quad = lane >> 4;
  const int e0   = b * 64;
  const int cb   = wave * 32;

  bf16x8 B1[2][6];
#pragma unroll
  for (int nl = 0; nl < 2; ++nl)
#pragma unroll
    for (int ks = 0; ks < 6; ++ks)
      B1[nl][ks] = *(const bf16x8*)(w1 + (size_t)(cb + nl * 16 + row) * 192 +
                                    ks * 32 + quad * 8);

  floatx4 acc[4][2];
#pragma unroll
  for (int m = 0; m < 4; ++m)
#pragma unroll
    for (int nl = 0; nl < 2; ++nl) acc[m][nl] = (floatx4){0.f, 0.f, 0.f, 0.f};

#pragma unroll
  for (int ks = 0; ks < 6; ++ks) {
    bf16x8 a[4];
#pragma unroll
    for (int m = 0; m < 4; ++m) {
      if (ks < 4) {
        a[m] = *(const bf16x8*)&meanS[m * 16 + row][ks * 32 + quad * 8];
      } else {
        int e = e0 + m * 16 + row;
        a[m] = *(const bf16x8*)(attr_bf + (size_t)e * 64 + (ks - 4) * 32 + quad * 8);
      }
    }
#pragma unroll
    for (int m = 0; m < 4; ++m)
#pragma unroll
      for (int nl = 0; nl < 2; ++nl)
        acc[m][nl] = __builtin_amdgcn_mfma_f32_16x16x32_bf16(a[m], B1[nl][ks],
                                                             acc[m][nl], 0, 0, 0);
  }
  __syncthreads();   // all meanS reads done before h1 overlay writes

#pragma unroll
  for (int nl = 0; nl < 2; ++nl) {
    float bias = b1[cb + nl * 16 + row];
#pragma unroll
    for (int m = 0; m < 4; ++m)
#pragma unroll
      for (int r = 0; r < 4; ++r)
        h1s[m * 16 + quad * 4 + r][cb + nl * 16 + row] =
            (short)f2bf(fmaxf(acc[m][nl][r] + bias, 0.0f));
  }

  bf16x8 B2[2][4];
#pragma unroll
  for (int nl = 0; nl < 2; ++nl)
#pragma unroll
    for (int ks = 0; ks < 4; ++ks)
      B2[nl][ks] = *(const bf16x8*)(w2 + (size_t)(cb + nl * 16 + row) * 128 +
                                    ks * 32 + quad * 8);
  __syncthreads();

  floatx4 acc2[4][2];
#pragma unroll
  for (int m = 0; m < 4; ++m)
#pragma unroll
    for (int nl = 0; nl < 2; ++nl) acc2[m][nl] = (floatx4){0.f, 0.f, 0.f, 0.f};

#pragma unroll
  for (int ks = 0; ks < 4; ++ks) {
    bf16x8 a[4];
#pragma unroll
    for (int m = 0; m < 4; ++m)
      a[m] = *(const bf16x8*)&h1s[m * 16 + row][ks * 32 + quad * 8];
#pragma unroll
    for (int m = 0; m < 4; ++m)
#pragma unroll
      for (int nl = 0; nl < 2; ++nl)
        acc2[m][nl] = __builtin_amdgcn_mfma_f32_16x16x32_bf16(a[m], B2[nl][ks],
                                                              acc2[m][nl], 0, 0, 0);
  }

#pragma unroll
  for (int nl = 0; nl < 2; ++nl) {
    int col = cb + nl * 16 + row;
    float bias = b2[col];
#pragma unroll
    for (int m = 0; m < 4; ++m)
#pragma unroll
      for (int r = 0; r < 4; ++r)
        edge_msg[(size_t)(e0 + m * 16 + quad * 4 + r) * 128 + col] =
            f2bf(acc2[m][nl][r] + bias);
  }
}

// ---------------------------------------------------------------------------
// Fused node: quarter-owned-segment gather on edge_msg rows + node MLP + LN.
// LDS ~26.1KB -> 5 blocks/CU: h1 overlays meanS, part overlays raw.
// ---------------------------------------------------------------------------
__global__ __launch_bounds__(256, 5) void k_node_fused(
    const unsigned short* __restrict__ emsg, const short* __restrict__ xh_bf,
    const unsigned* __restrict__ pairs, const int* __restrict__ bcnt,
    const short* __restrict__ wp, const float* __restrict__ bp,
    const short* __restrict__ wn1, const float* __restrict__ bn1,
    const short* __restrict__ wn2, const float* __restrict__ bn2,
    const float* __restrict__ gamma, const float* __restrict__ beta,
    float* __restrict__ out) {
  __shared__ short meanS[64][136];     // 17408 B; doubles as h1
  __shared__ unsigned raw[CAP_H];      // 4096 B; doubles as part[64][4] (2048 B)
  __shared__ unsigned sortedp[CAP_H];  // 4096
  __shared__ int cnts[65];
  __shared__ int curs[64];
  short (*h1s)[136] = meanS;
  float2 (*part)[4] = (float2(*)[4])raw;

  const int b = blockIdx.x;
  const int t = threadIdx.x;

  int total = 0;
#pragma unroll
  for (int x = 0; x < 8; ++x) {
    int c = min(bcnt[((size_t)x * NBUCK_H + b) * BCNT_PAD], SUBCAP_H);
    const unsigned* src = pairs + ((size_t)x * NBUCK_H + b) * SUBCAP_H;
    for (int j = t; j < c; j += 256) {
      int d = total + j;
      if (d < CAP_H) raw[d] = src[j];
    }
    total += c;
  }
  const int cnt = min(total, CAP_H);
  if (t <= 64) cnts[t] = 0;
  __syncthreads();
  for (int j = t; j < cnt; j += 256)
    atomicAdd(&cnts[(raw[j] >> 24) + 1], 1);
  __syncthreads();
  for (int d = 1; d <= 64; d <<= 1) {
    int v = 0;
    if (t <= 64 && t >= d) v = cnts[t - d];
    __syncthreads();
    if (t <= 64) cnts[t] += v;
    __syncthreads();
  }
  if (t < 64) curs[t] = cnts[t];
  __syncthreads();
  for (int j = t; j < cnt; j += 256) {
    unsigned p = raw[j];
    int d = atomicAdd(&curs[p >> 24], 1);
    sortedp[d] = (p & 0xFFFFFFu) << 8;   // byte offset of 256B row
  }
  __syncthreads();

  const int wave = t >> 6, lane = t & 63;
  const int ql = lane & 15;
  GATHER_QSEG(emsg);
  __syncthreads();

  // ---- node MLP + LN (A from LDS) ----
  const int row  = lane & 15;
  const int quad = lane >> 4;
  const int n0   = b * 64;
  const int cb   = wave * 32;

  bf16x8 B1[2][4];
#pragma unroll
  for (int nl = 0; nl < 2; ++nl)
#pragma unroll
    for (int ks = 0; ks < 4; ++ks)
      B1[nl][ks] = *(const bf16x8*)(wn1 + (size_t)(cb + nl * 16 + row) * 128 +
                                    ks * 32 + quad * 8);

  floatx4 acc[4][2];
#pragma unroll
  for (int m = 0; m < 4; ++m)
#pragma unroll
    for (int nl = 0; nl < 2; ++nl) acc[m][nl] = (floatx4){0.f, 0.f, 0.f, 0.f};

#pragma unroll
  for (int ks = 0; ks < 4; ++ks) {
    bf16x8 a[4];
#pragma unroll
    for (int m = 0; m < 4; ++m)
      a[m] = *(const bf16x8*)&meanS[m * 16 + row][ks * 32 + quad * 8];
#pragma unroll
    for (int m = 0; m < 4; ++m)
#pragma unroll
      for (int nl = 0; nl < 2; ++nl)
        acc[m][nl] = __builtin_amdgcn_mfma_f32_16x16x32_bf16(a[m], B1[nl][ks],
                                                             acc[m][nl], 0, 0, 0);
  }
  __syncthreads();   // all meanS reads done before h1 overlay writes

#pragma unroll
  for (int nl = 0; nl < 2; ++nl) {
    float bias = bn1[cb + nl * 16 + row];
#pragma unroll
    for (int m = 0; m < 4; ++m)
#pragma unroll
      for (int r = 0; r < 4; ++r)
        h1s[m * 16 + quad * 4 + r][cb + nl * 16 + row] =
            (short)f2bf(fmaxf(acc[m][nl][r] + bias, 0.0f));
  }

  bf16x8 B2[2][4], Bp[2][4];
#pragma unroll
  for (int nl = 0; nl < 2; ++nl)
#pragma unroll
    for (int ks = 0; ks < 4; ++ks) {
      B2[nl][ks] = *(const bf16x8*)(wn2 + (size_t)(cb + nl * 16 + row) * 128 +
                                    ks * 32 + quad * 8);
      Bp[nl][ks] = *(const bf16x8*)(wp + (size_t)(cb + nl * 16 + row) * 128 +
                                    ks * 32 + quad * 8);
    }
  __syncthreads();

  floatx4 acc2[4][2];
#pragma unroll
  for (int m = 0; m < 4; ++m)
#pragma unroll
    for (int nl = 0; nl < 2; ++nl) acc2[m][nl] = (floatx4){0.f, 0.f, 0.f, 0.f};

#pragma unroll
  for (int ks = 0; ks < 4; ++ks) {
    bf16x8 at[4], ax[4];
#pragma unroll
    for (int m = 0; m < 4; ++m) {
      at[m] = *(const bf16x8*)&h1s[m * 16 + row][ks * 32 + quad * 8];
      int n = n0 + m * 16 + row;
      ax[m] = *(const bf16x8*)(xh_bf + (size_t)n * 128 + ks * 32 + quad * 8);
    }
#pragma unroll
    for (int m = 0; m < 4; ++m)
#pragma unroll
      for (int nl = 0; nl < 2; ++nl) {
        acc2[m][nl] = __builtin_amdgcn_mfma_f32_16x16x32_bf16(at[m], B2[nl][ks],
                                                              acc2[m][nl], 0, 0, 0);
        acc2[m][nl] = __builtin_amdgcn_mfma_f32_16x16x32_bf16(ax[m], Bp[nl][ks],
                                                              acc2[m][nl], 0, 0, 0);
      }
  }

  float z[4][2][4];
#pragma unroll
  for (int m = 0; m < 4; ++m) {
    float s[4], ss[4];
#pragma unroll
    for (int r = 0; r < 4; ++r) { s[r] = 0.f; ss[r] = 0.f; }
#pragma unroll
    for (int nl = 0; nl < 2; ++nl) {
      float bias = bp[cb + nl * 16 + row] + bn2[cb + nl * 16 + row];
#pragma unroll
      for (int r = 0; r < 4; ++r) {
        float v = fmaxf(acc2[m][nl][r] + bias, 0.0f);
        z[m][nl][r] = v;
        s[r] += v;
        ss[r] += v * v;
      }
    }
#pragma unroll
    for (int r = 0; r < 4; ++r) {
#pragma unroll
      for (int msk = 1; msk < 16; msk <<= 1) {
        s[r]  += __shfl_xor(s[r],  msk, 64);
        ss[r] += __shfl_xor(ss[r], msk, 64);
      }
      if (row == 0) part[m * 16 + quad * 4 + r][wave] = make_float2(s[r], ss[r]);
    }
  }
  __syncthreads();

#pragma unroll
  for (int m = 0; m < 4; ++m)
#pragma unroll
    for (int r = 0; r < 4; ++r) {
      int rr = m * 16 + quad * 4 + r;
      float2 p0 = part[rr][0], p1 = part[rr][1], p2 = part[rr][2], p3 = part[rr][3];
      float mean = (p0.x + p1.x + p2.x + p3.x) * (1.0f / 128.0f);
      float var  = (p0.y + p1.y + p2.y + p3.y) * (1.0f / 128.0f) - mean * mean;
      float rstd = rsqrtf(var + LN_EPS);
      int n = n0 + rr;
      if (n < H_N) {
#pragma unroll
        for (int nl = 0; nl < 2; ++nl) {
          int col = cb + nl * 16 + row;
          out[(size_t)n * 128 + col] =
              (z[m][nl][r] - mean) * rstd * gamma[col] + beta[col];
        }
      }
    }
}

// ---------------------------------------------------------------------------
extern "C" void kernel_launch(void* const* d_in, const int* in_sizes, int n_in,
                              void* d_out, int out_size, void* d_ws, size_t ws_size,
                              hipStream_t stream) {
  const float* x_h   = (const float*)d_in[0];
  const float* attr  = (const float*)d_in[1];
  const float* Wp    = (const float*)d_in[2];
  const float* bp    = (const float*)d_in[3];
  const float* We1   = (const float*)d_in[4];
  const float* be1   = (const float*)d_in[5];
  const float* We2   = (const float*)d_in[6];
  const float* be2   = (const float*)d_in[7];
  const float* Wn1   = (const float*)d_in[8];
  const float* bn1   = (const float*)d_in[9];
  const float* Wn2   = (const float*)d_in[10];
  const float* bn2   = (const float*)d_in[11];
  const float* gamma = (const float*)d_in[12];
  const float* beta  = (const float*)d_in[13];
  const int*   fg    = (const int*)d_in[14];
  const int*   res   = (const int*)d_in[15];
  float* out = (float*)d_out;

  // ---- workspace layout ----
  int* bcnt_e = (int*)d_ws;                                  // 8*NBUCK_E*16
  int* bcnt_h = bcnt_e + (size_t)8 * NBUCK_E * BCNT_PAD;     // 8*NBUCK_H*16
  unsigned* pairs_e = (unsigned*)(bcnt_h + (size_t)8 * NBUCK_H * BCNT_PAD);
  unsigned* pairs_h = pairs_e + (size_t)8 * NBUCK_E * SUBCAP_E;
  unsigned short* xh_bf    = (unsigned short*)(pairs_h + (size_t)8 * NBUCK_H * SUBCAP_H);
  unsigned short* edge_msg = xh_bf + (size_t)H_N * 128;
  short* w1  = (short*)(edge_msg + (size_t)E_N * 128);
  short* w2  = w1 + 128 * 192;
  short* wn1 = w2 + 128 * 128;
  short* wn2 = wn1 + 128 * 128;
  short* wp  = wn2 + 128 * 128;
  short* attr_bf = wp + 128 * 128;                           // E_N*64 bf16

  k_prep<<<PREP_TOTAL, 256, 0, stream>>>(
      (const float4*)x_h, xh_bf,
      (const float4*)attr, (unsigned short*)attr_bf,
      (const float4*)We1, (unsigned short*)w1,
      (const float4*)We2, (unsigned short*)w2,
      (const float4*)Wn1, (unsigned short*)wn1,
      (const float4*)Wn2, (unsigned short*)wn2,
      (const float4*)Wp, (unsigned short*)wp,
      (intx4*)bcnt_e);

  k_bucket<<<(NI_N / 4 + 255) / 256, 256, 0, stream>>>(fg, res, bcnt_e, bcnt_h,
                                                       pairs_e, pairs_h);

  k_edge_fused<<<NBUCK_E, 256, 0, stream>>>(xh_bf, attr_bf, pairs_e, bcnt_e,
                                            w1, be1, w2, be2, edge_msg);
  k_node_fused<<<NBUCK_H, 256, 0, stream>>>(edge_msg, (const short*)xh_bf,
                                            pairs_h, bcnt_h,
                                            wp, bp, wn1, bn1, wn2, bn2,
                                            gamma, beta, out);
}

// Round 11
// 460.175 us; speedup vs baseline: 1.0328x; 1.0163x over previous
//
#include <hip/hip_runtime.h>

#define H_N   100000
#define E_N   200000
#define NI_N  1000000
#define LN_EPS 1e-5f

// Edge buckets: 64 edges each -> one MLP tile per bucket. 200000/64 = 3125 exactly.
#define NBUCK_E 3125
// Node buckets: 64 nodes each. ceil(100000/64) = 1563.
#define NBUCK_H 1563
#define SUBCAP_E 128       // per-XCD sub-bucket cap (mean 40, sigma ~6)
#define SUBCAP_H 192       // per-XCD sub-bucket cap (mean 80, sigma ~9)
#define CAP_E 512          // total per-bucket cap (mean 320, sigma ~18)
#define CAP_H 1024         // total per-bucket cap (mean 640, sigma ~25)
#define BCNT_PAD 16        // one counter per 64B line: kills same-line atomic RMW serialization

typedef __attribute__((ext_vector_type(8))) short bf16x8;
typedef __attribute__((ext_vector_type(4))) float floatx4;
typedef __attribute__((ext_vector_type(4))) int intx4;
typedef __attribute__((ext_vector_type(4))) unsigned uintx4;

__device__ inline unsigned short f2bf(float f) {
  unsigned u = __builtin_bit_cast(unsigned, f);
  u += 0x7fffu + ((u >> 16) & 1u);           // round-to-nearest-even
  return (unsigned short)(u >> 16);
}
__device__ inline float bf2f(unsigned short s) {
  unsigned u = ((unsigned)s) << 16;
  return __builtin_bit_cast(float, u);
}
__device__ inline unsigned get_xcc() {
  unsigned x;
  asm volatile("s_getreg_b32 %0, hwreg(HW_REG_XCC_ID)" : "=s"(x));
  return x & 7;
}

// ---------------------------------------------------------------------------
// Prep kernel: one launch does all fp32->bf16 conversions + bcnt zeroing.
// (R9 lesson: do NOT merge with k_bucket — cvt streaming traffic contends
// with bucket's atomic RMW path in TCC; merged ran 170us vs ~120us serial.)
// ---------------------------------------------------------------------------
#define PREP_XH_BLKS   12500   // H_N*128/4/256
#define PREP_ATTR_BLKS 12500   // E_N*64/4/256
#define PREP_W1_BLKS   24      // 128*192/4/256
#define PREP_W_BLKS    16      // 128*128/4/256
#define PREP_ZERO_BLKS 586     // (8*NBUCK_E+8*NBUCK_H)*BCNT_PAD/4/256
#define PREP_TOTAL (PREP_XH_BLKS + PREP_ATTR_BLKS + PREP_W1_BLKS + 4*PREP_W_BLKS + PREP_ZERO_BLKS)

__device__ inline void cvt4(const float4* __restrict__ src,
                            unsigned short* __restrict__ dst, int i, int n4) {
  if (i >= n4) return;
  float4 v = src[i];
  union { unsigned short us[4]; unsigned long long u64; } p;
  p.us[0] = f2bf(v.x); p.us[1] = f2bf(v.y);
  p.us[2] = f2bf(v.z); p.us[3] = f2bf(v.w);
  *(unsigned long long*)(dst + (size_t)i * 4) = p.u64;
}

__global__ __launch_bounds__(256) void k_prep(
    const float4* __restrict__ x_h, unsigned short* __restrict__ xh_bf,
    const float4* __restrict__ attr, unsigned short* __restrict__ attr_bf,
    const float4* __restrict__ We1, unsigned short* __restrict__ w1,
    const float4* __restrict__ We2, unsigned short* __restrict__ w2,
    const float4* __restrict__ Wn1, unsigned short* __restrict__ wn1,
    const float4* __restrict__ Wn2, unsigned short* __restrict__ wn2,
    const float4* __restrict__ Wp, unsigned short* __restrict__ wp,
    intx4* __restrict__ bcnt_zero) {
  int blk = blockIdx.x;
  int tid = threadIdx.x;
  if (blk < PREP_XH_BLKS) {
    cvt4(x_h, xh_bf, blk * 256 + tid, H_N * 128 / 4);
    return;
  }
  blk -= PREP_XH_BLKS;
  if (blk < PREP_ATTR_BLKS) {
    cvt4(attr, attr_bf, blk * 256 + tid, E_N * 64 / 4);
    return;
  }
  blk -= PREP_ATTR_BLKS;
  if (blk < PREP_W1_BLKS) {
    cvt4(We1, w1, blk * 256 + tid, 128 * 192 / 4);
    return;
  }
  blk -= PREP_W1_BLKS;
  if (blk < PREP_W_BLKS) {
    cvt4(We2, w2, blk * 256 + tid, 128 * 128 / 4);
    return;
  }
  blk -= PREP_W_BLKS;
  if (blk < PREP_W_BLKS) {
    cvt4(Wn1, wn1, blk * 256 + tid, 128 * 128 / 4);
    return;
  }
  blk -= PREP_W_BLKS;
  if (blk < PREP_W_BLKS) {
    cvt4(Wn2, wn2, blk * 256 + tid, 128 * 128 / 4);
    return;
  }
  blk -= PREP_W_BLKS;
  if (blk < PREP_W_BLKS) {
    cvt4(Wp, wp, blk * 256 + tid, 128 * 128 / 4);
    return;
  }
  blk -= PREP_W_BLKS;
  {
    int i = blk * 256 + tid;
    int n = (8 * NBUCK_E + 8 * NBUCK_H) * BCNT_PAD / 4;
    if (i < n) bcnt_zero[i] = (intx4){0, 0, 0, 0};
  }
}

// ---------------------------------------------------------------------------
// Bucket binning, XCD-local, 4 incidences/thread. Interleaved atomic->store
// (R10 lesson: hoisting all 8 atomics ahead of the stores REGRESSED 25us —
// in-order vmcnt makes every store wait for the whole atomic batch; the
// compiler's interleaved schedule overlaps store j with atomic j+1).
// ---------------------------------------------------------------------------
__global__ __launch_bounds__(256) void k_bucket(
    const int* __restrict__ fg, const int* __restrict__ res,
    int* __restrict__ bcnt_e, int* __restrict__ bcnt_h,
    unsigned* __restrict__ pairs_e, unsigned* __restrict__ pairs_h) {
  int i0 = (blockIdx.x * 256 + threadIdx.x) * 4;
  if (i0 >= NI_N) return;
  unsigned xcc = get_xcc();
  intx4 f4 = __builtin_nontemporal_load((const intx4*)(fg + i0));
  intx4 r4 = __builtin_nontemporal_load((const intx4*)(res + i0));
#pragma unroll
  for (int j = 0; j < 4; ++j) {
    int f = f4[j], r = r4[j];
    int be = r >> 6, se = r & 63;
    int pe = atomicAdd(bcnt_e + ((size_t)xcc * NBUCK_E + be) * BCNT_PAD, 1);
    if (pe < SUBCAP_E)
      __builtin_nontemporal_store(((unsigned)se << 24) | (unsigned)f,
          &pairs_e[((size_t)xcc * NBUCK_E + be) * SUBCAP_E + pe]);
    int bh = f >> 6, sh = f & 63;
    int ph = atomicAdd(bcnt_h + ((size_t)xcc * NBUCK_H + bh) * BCNT_PAD, 1);
    if (ph < SUBCAP_H)
      __builtin_nontemporal_store(((unsigned)sh << 24) | (unsigned)r,
          &pairs_h[((size_t)xcc * NBUCK_H + bh) * SUBCAP_H + ph]);
  }
}

// ---------------------------------------------------------------------------
// Quarter-owned-segment gather: each 16-lane quarter (qid = t>>4, 0..15)
// owns segments qid, qid+16, qid+32, qid+48 and walks ALL their entries:
// one dwordx4 load covers the full 256B row (lane ql = 16B slice). Loads
// within a quarter are independent; 4 quarters run concurrently.
// NOTE (R8 post-mortem): three ILP structures all land at ~110-122us with
// constant FETCH_SIZE -> the gather is throughput-bound on the random-256B
// fetch path (~2.0-2.3 TB/s), not latency-bound. Do not re-engineer ILP.
// ---------------------------------------------------------------------------
#define GATHER_QSEG(basePtr)                                                   \
  {                                                                            \
    const int qid = (t >> 4);                                                  \
    for (int k = 0; k < 4; ++k) {                                              \
      int s = qid + 16 * k;                                                    \
      int o = cnts[s], e = cnts[s + 1];                                        \
      float a[8];                                                              \
      _Pragma("unroll")                                                        \
      for (int x = 0; x < 8; ++x) a[x] = 0.f;                                  \
      int j = o;                                                               \
      for (; j + 1 < e; j += 2) {                                              \
        unsigned off0 = sortedp[j], off1 = sortedp[j + 1];                     \
        uintx4 v0 = *(const uintx4*)((const char*)(basePtr) + off0 + ql * 16); \
        uintx4 v1 = *(const uintx4*)((const char*)(basePtr) + off1 + ql * 16); \
        _Pragma("unroll")                                                      \
        for (int x = 0; x < 4; ++x) {                                          \
          a[2 * x]     += bf2f((unsigned short)(v0[x] & 0xffffu)) +            \
                          bf2f((unsigned short)(v1[x] & 0xffffu));             \
          a[2 * x + 1] += bf2f((unsigned short)(v0[x] >> 16)) +                \
                          bf2f((unsigned short)(v1[x] >> 16));                 \
        }                                                                      \
      }                                                                        \
      if (j < e) {                                                             \
        unsigned off0 = sortedp[j];                                            \
        uintx4 v0 = *(const uintx4*)((const char*)(basePtr) + off0 + ql * 16); \
        _Pragma("unroll")                                                      \
        for (int x = 0; x < 4; ++x) {                                          \
          a[2 * x]     += bf2f((unsigned short)(v0[x] & 0xffffu));             \
          a[2 * x + 1] += bf2f((unsigned short)(v0[x] >> 16));                 \
        }                                                                      \
      }                                                                        \
      float inv = (e > o) ? 1.0f / (float)(e - o) : 0.0f;                      \
      uintx4 ov;                                                               \
      _Pragma("unroll")                                                        \
      for (int x = 0; x < 4; ++x)                                              \
        ov[x] = (unsigned)f2bf(a[2 * x] * inv) |                               \
                ((unsigned)f2bf(a[2 * x + 1] * inv) << 16);                    \
      *(uintx4*)&meanS[s][ql * 8] = ov;                                        \
    }                                                                          \
  }

// ---------------------------------------------------------------------------
// Fused edge: concat -> counting sort -> quarter-owned-segment gather-mean
// -> edge MLP. h1 overlays meanS (barrier-separated). LDS ~22KB, 6 blk/CU.
// ---------------------------------------------------------------------------
__global__ __launch_bounds__(256, 6) void k_edge_fused(
    const unsigned short* __restrict__ xh, const short* __restrict__ attr_bf,
    const unsigned* __restrict__ pairs, const int* __restrict__ bcnt,
    const short* __restrict__ w1, const float* __restrict__ b1,
    const short* __restrict__ w2, const float* __restrict__ b2,
    unsigned short* __restrict__ edge_msg) {
  __shared__ short meanS[64][136];     // 17408 B; doubles as h1 after barrier
  __shared__ unsigned raw[CAP_E];      // 2048
  __shared__ unsigned sortedp[CAP_E];  // 2048
  __shared__ int cnts[65];
  __shared__ int curs[64];
  short (*h1s)[136] = meanS;

  const int b = blockIdx.x;
  const int t = threadIdx.x;

  // ---- concat 8 per-XCD sub-lists ----
  int total = 0;
#pragma unroll
  for (int x = 0; x < 8; ++x) {
    int c = min(bcnt[((size_t)x * NBUCK_E + b) * BCNT_PAD], SUBCAP_E);
    const unsigned* src = pairs + ((size_t)x * NBUCK_E + b) * SUBCAP_E;
    for (int j = t; j < c; j += 256) {
      int d = total + j;
      if (d < CAP_E) raw[d] = src[j];
    }
    total += c;
  }
  const int cnt = min(total, CAP_E);
  if (t <= 64) cnts[t] = 0;
  __syncthreads();
  for (int j = t; j < cnt; j += 256)
    atomicAdd(&cnts[(raw[j] >> 24) + 1], 1);
  __syncthreads();
  for (int d = 1; d <= 64; d <<= 1) {
    int v = 0;
    if (t <= 64 && t >= d) v = cnts[t - d];
    __syncthreads();
    if (t <= 64) cnts[t] += v;
    __syncthreads();
  }
  if (t < 64) curs[t] = cnts[t];
  __syncthreads();
  for (int j = t; j < cnt; j += 256) {
    unsigned p = raw[j];
    int d = atomicAdd(&curs[p >> 24], 1);
    sortedp[d] = (p & 0xFFFFFFu) << 8;   // byte offset of 256B row
  }
  __syncthreads();

  // ---- quarter-owned-segment gather-mean into LDS tile ----
  const int wave = t >> 6, lane = t & 63;
  const int ql = lane & 15;
  GATHER_QSEG(xh);
  __syncthreads();

  // ---- edge MLP (A from LDS) ----
  const int row  = lane & 15;
  const int quad = lane >> 4;
  const int e0   = b * 64;
  const int cb   = wave * 32;

  bf16x8 B1[2][6];
#pragma unroll
  for (int nl = 0; nl < 2; ++nl)
#pragma unroll
    for (int ks = 0; ks < 6; ++ks)
      B1[nl][ks] = *(const bf16x8*)(w1 + (size_t)(cb + nl * 16 + row) * 192 +
                                    ks * 32 + quad * 8);

  floatx4 acc[4][2];
#pragma unroll
  for (int m = 0; m < 4; ++m)
#pragma unroll
    for (int nl = 0; nl < 2; ++nl) acc[m][nl] = (floatx4){0.f, 0.f, 0.f, 0.f};

#pragma unroll
  for (int ks = 0; ks < 6; ++ks) {
    bf16x8 a[4];
#pragma unroll
    for (int m = 0; m < 4; ++m) {
      if (ks < 4) {
        a[m] = *(const bf16x8*)&meanS[m * 16 + row][ks * 32 + quad * 8];
      } else {
        int e = e0 + m * 16 + row;
        a[m] = *(const bf16x8*)(attr_bf + (size_t)e * 64 + (ks - 4) * 32 + quad * 8);
      }
    }
#pragma unroll
    for (int m = 0; m < 4; ++m)
#pragma unroll
      for (int nl = 0; nl < 2; ++nl)
        acc[m][nl] = __builtin_amdgcn_mfma_f32_16x16x32_bf16(a[m], B1[nl][ks],
                                                             acc[m][nl], 0, 0, 0);
  }
  __syncthreads();   // all meanS reads done before h1 overlay writes

#pragma unroll
  for (int nl = 0; nl < 2; ++nl) {
    float bias = b1[cb + nl * 16 + row];
#pragma unroll
    for (int m = 0; m < 4; ++m)
#pragma unroll
      for (int r = 0; r < 4; ++r)
        h1s[m * 16 + quad * 4 + r][cb + nl * 16 + row] =
            (short)f2bf(fmaxf(acc[m][nl][r] + bias, 0.0f));
  }

  bf16x8 B2[2][4];
#pragma unroll
  for (int nl = 0; nl < 2; ++nl)
#pragma unroll
    for (int ks = 0; ks < 4; ++ks)
      B2[nl][ks] = *(const bf16x8*)(w2 + (size_t)(cb + nl * 16 + row) * 128 +
                                    ks * 32 + quad * 8);
  __syncthreads();

  floatx4 acc2[4][2];
#pragma unroll
  for (int m = 0; m < 4; ++m)
#pragma unroll
    for (int nl = 0; nl < 2; ++nl) acc2[m][nl] = (floatx4){0.f, 0.f, 0.f, 0.f};

#pragma unroll
  for (int ks = 0; ks < 4; ++ks) {
    bf16x8 a[4];
#pragma unroll
    for (int m = 0; m < 4; ++m)
      a[m] = *(const bf16x8*)&h1s[m * 16 + row][ks * 32 + quad * 8];
#pragma unroll
    for (int m = 0; m < 4; ++m)
#pragma unroll
      for (int nl = 0; nl < 2; ++nl)
        acc2[m][nl] = __builtin_amdgcn_mfma_f32_16x16x32_bf16(a[m], B2[nl][ks],
                                                              acc2[m][nl], 0, 0, 0);
  }

#pragma unroll
  for (int nl = 0; nl < 2; ++nl) {
    int col = cb + nl * 16 + row;
    float bias = b2[col];
#pragma unroll
    for (int m = 0; m < 4; ++m)
#pragma unroll
      for (int r = 0; r < 4; ++r)
        edge_msg[(size_t)(e0 + m * 16 + quad * 4 + r) * 128 + col] =
            f2bf(acc2[m][nl][r] + bias);
  }
}

// ---------------------------------------------------------------------------
// Fused node: quarter-owned-segment gather on edge_msg rows + node MLP + LN.
// LDS ~26.1KB -> 5 blocks/CU: h1 overlays meanS, part overlays raw.
// ---------------------------------------------------------------------------
__global__ __launch_bounds__(256, 5) void k_node_fused(
    const unsigned short* __restrict__ emsg, const short* __restrict__ xh_bf,
    const unsigned* __restrict__ pairs, const int* __restrict__ bcnt,
    const short* __restrict__ wp, const float* __restrict__ bp,
    const short* __restrict__ wn1, const float* __restrict__ bn1,
    const short* __restrict__ wn2, const float* __restrict__ bn2,
    const float* __restrict__ gamma, const float* __restrict__ beta,
    float* __restrict__ out) {
  __shared__ short meanS[64][136];     // 17408 B; doubles as h1
  __shared__ unsigned raw[CAP_H];      // 4096 B; doubles as part[64][4] (2048 B)
  __shared__ unsigned sortedp[CAP_H];  // 4096
  __shared__ int cnts[65];
  __shared__ int curs[64];
  short (*h1s)[136] = meanS;
  float2 (*part)[4] = (float2(*)[4])raw;

  const int b = blockIdx.x;
  const int t = threadIdx.x;

  int total = 0;
#pragma unroll
  for (int x = 0; x < 8; ++x) {
    int c = min(bcnt[((size_t)x * NBUCK_H + b) * BCNT_PAD], SUBCAP_H);
    const unsigned* src = pairs + ((size_t)x * NBUCK_H + b) * SUBCAP_H;
    for (int j = t; j < c; j += 256) {
      int d = total + j;
      if (d < CAP_H) raw[d] = src[j];
    }
    total += c;
  }
  const int cnt = min(total, CAP_H);
  if (t <= 64) cnts[t] = 0;
  __syncthreads();
  for (int j = t; j < cnt; j += 256)
    atomicAdd(&cnts[(raw[j] >> 24) + 1], 1);
  __syncthreads();
  for (int d = 1; d <= 64; d <<= 1) {
    int v = 0;
    if (t <= 64 && t >= d) v = cnts[t - d];
    __syncthreads();
    if (t <= 64) cnts[t] += v;
    __syncthreads();
  }
  if (t < 64) curs[t] = cnts[t];
  __syncthreads();
  for (int j = t; j < cnt; j += 256) {
    unsigned p = raw[j];
    int d = atomicAdd(&curs[p >> 24], 1);
    sortedp[d] = (p & 0xFFFFFFu) << 8;   // byte offset of 256B row
  }
  __syncthreads();

  const int wave = t >> 6, lane = t & 63;
  const int ql = lane & 15;
  GATHER_QSEG(emsg);
  __syncthreads();

  // ---- node MLP + LN (A from LDS) ----
  const int row  = lane & 15;
  const int quad = lane >> 4;
  const int n0   = b * 64;
  const int cb   = wave * 32;

  bf16x8 B1[2][4];
#pragma unroll
  for (int nl = 0; nl < 2; ++nl)
#pragma unroll
    for (int ks = 0; ks < 4; ++ks)
      B1[nl][ks] = *(const bf16x8*)(wn1 + (size_t)(cb + nl * 16 + row) * 128 +
                                    ks * 32 + quad * 8);

  floatx4 acc[4][2];
#pragma unroll
  for (int m = 0; m < 4; ++m)
#pragma unroll
    for (int nl = 0; nl < 2; ++nl) acc[m][nl] = (floatx4){0.f, 0.f, 0.f, 0.f};

#pragma unroll
  for (int ks = 0; ks < 4; ++ks) {
    bf16x8 a[4];
#pragma unroll
    for (int m = 0; m < 4; ++m)
      a[m] = *(const bf16x8*)&meanS[m * 16 + row][ks * 32 + quad * 8];
#pragma unroll
    for (int m = 0; m < 4; ++m)
#pragma unroll
      for (int nl = 0; nl < 2; ++nl)
        acc[m][nl] = __builtin_amdgcn_mfma_f32_16x16x32_bf16(a[m], B1[nl][ks],
                                                             acc[m][nl], 0, 0, 0);
  }
  __syncthreads();   // all meanS reads done before h1 overlay writes

#pragma unroll
  for (int nl = 0; nl < 2; ++nl) {
    float bias = bn1[cb + nl * 16 + row];
#pragma unroll
    for (int m = 0; m < 4; ++m)
#pragma unroll
      for (int r = 0; r < 4; ++r)
        h1s[m * 16 + quad * 4 + r][cb + nl * 16 + row] =
            (short)f2bf(fmaxf(acc[m][nl][r] + bias, 0.0f));
  }

  bf16x8 B2[2][4], Bp[2][4];
#pragma unroll
  for (int nl = 0; nl < 2; ++nl)
#pragma unroll
    for (int ks = 0; ks < 4; ++ks) {
      B2[nl][ks] = *(const bf16x8*)(wn2 + (size_t)(cb + nl * 16 + row) * 128 +
                                    ks * 32 + quad * 8);
      Bp[nl][ks] = *(const bf16x8*)(wp + (size_t)(cb + nl * 16 + row) * 128 +
                                    ks * 32 + quad * 8);
    }
  __syncthreads();

  floatx4 acc2[4][2];
#pragma unroll
  for (int m = 0; m < 4; ++m)
#pragma unroll
    for (int nl = 0; nl < 2; ++nl) acc2[m][nl] = (floatx4){0.f, 0.f, 0.f, 0.f};

#pragma unroll
  for (int ks = 0; ks < 4; ++ks) {
    bf16x8 at[4], ax[4];
#pragma unroll
    for (int m = 0; m < 4; ++m) {
      at[m] = *(const bf16x8*)&h1s[m * 16 + row][ks * 32 + quad * 8];
      int n = n0 + m * 16 + row;
      ax[m] = *(const bf16x8*)(xh_bf + (size_t)n * 128 + ks * 32 + quad * 8);
    }
#pragma unroll
    for (int m = 0; m < 4; ++m)
#pragma unroll
      for (int nl = 0; nl < 2; ++nl) {
        acc2[m][nl] = __builtin_amdgcn_mfma_f32_16x16x32_bf16(at[m], B2[nl][ks],
                                                              acc2[m][nl], 0, 0, 0);
        acc2[m][nl] = __builtin_amdgcn_mfma_f32_16x16x32_bf16(ax[m], Bp[nl][ks],
                                                              acc2[m][nl], 0, 0, 0);
      }
  }

  float z[4][2][4];
#pragma unroll
  for (int m = 0; m < 4; ++m) {
    float s[4], ss[4];
#pragma unroll
    for (int r = 0; r < 4; ++r) { s[r] = 0.f; ss[r] = 0.f; }
#pragma unroll
    for (int nl = 0; nl < 2; ++nl) {
      float bias = bp[cb + nl * 16 + row] + bn2[cb + nl * 16 + row];
#pragma unroll
      for (int r = 0; r < 4; ++r) {
        float v = fmaxf(acc2[m][nl][r] + bias, 0.0f);
        z[m][nl][r] = v;
        s[r] += v;
        ss[r] += v * v;
      }
    }
#pragma unroll
    for (int r = 0; r < 4; ++r) {
#pragma unroll
      for (int msk = 1; msk < 16; msk <<= 1) {
        s[r]  += __shfl_xor(s[r],  msk, 64);
        ss[r] += __shfl_xor(ss[r], msk, 64);
      }
      if (row == 0) part[m * 16 + quad * 4 + r][wave] = make_float2(s[r], ss[r]);
    }
  }
  __syncthreads();

#pragma unroll
  for (int m = 0; m < 4; ++m)
#pragma unroll
    for (int r = 0; r < 4; ++r) {
      int rr = m * 16 + quad * 4 + r;
      float2 p0 = part[rr][0], p1 = part[rr][1], p2 = part[rr][2], p3 = part[rr][3];
      float mean = (p0.x + p1.x + p2.x + p3.x) * (1.0f / 128.0f);
      float var  = (p0.y + p1.y + p2.y + p3.y) * (1.0f / 128.0f) - mean * mean;
      float rstd = rsqrtf(var + LN_EPS);
      int n = n0 + rr;
      if (n < H_N) {
#pragma unroll
        for (int nl = 0; nl < 2; ++nl) {
          int col = cb + nl * 16 + row;
          out[(size_t)n * 128 + col] =
              (z[m][nl][r] - mean) * rstd * gamma[col] + beta[col];
        }
      }
    }
}

// ---------------------------------------------------------------------------
extern "C" void kernel_launch(void* const* d_in, const int* in_sizes, int n_in,
                              void* d_out, int out_size, void* d_ws, size_t ws_size,
                              hipStream_t stream) {
  const float* x_h   = (const float*)d_in[0];
  const float* attr  = (const float*)d_in[1];
  const float* Wp    = (const float*)d_in[2];
  const float* bp    = (const float*)d_in[3];
  const float* We1   = (const float*)d_in[4];
  const float* be1   = (const float*)d_in[5];
  const float* We2   = (const float*)d_in[6];
  const float* be2   = (const float*)d_in[7];
  const float* Wn1   = (const float*)d_in[8];
  const float* bn1   = (const float*)d_in[9];
  const float* Wn2   = (const float*)d_in[10];
  const float* bn2   = (const float*)d_in[11];
  const float* gamma = (const float*)d_in[12];
  const float* beta  = (const float*)d_in[13];
  const int*   fg    = (const int*)d_in[14];
  const int*   res   = (const int*)d_in[15];
  float* out = (float*)d_out;

  // ---- workspace layout ----
  int* bcnt_e = (int*)d_ws;                                  // 8*NBUCK_E*16
  int* bcnt_h = bcnt_e + (size_t)8 * NBUCK_E * BCNT_PAD;     // 8*NBUCK_H*16
  unsigned* pairs_e = (unsigned*)(bcnt_h + (size_t)8 * NBUCK_H * BCNT_PAD);
  unsigned* pairs_h = pairs_e + (size_t)8 * NBUCK_E * SUBCAP_E;
  unsigned short* xh_bf    = (unsigned short*)(pairs_h + (size_t)8 * NBUCK_H * SUBCAP_H);
  unsigned short* edge_msg = xh_bf + (size_t)H_N * 128;
  short* w1  = (short*)(edge_msg + (size_t)E_N * 128);
  short* w2  = w1 + 128 * 192;
  short* wn1 = w2 + 128 * 128;
  short* wn2 = wn1 + 128 * 128;
  short* wp  = wn2 + 128 * 128;
  short* attr_bf = wp + 128 * 128;                           // E_N*64 bf16

  k_prep<<<PREP_TOTAL, 256, 0, stream>>>(
      (const float4*)x_h, xh_bf,
      (const float4*)attr, (unsigned short*)attr_bf,
      (const float4*)We1, (unsigned short*)w1,
      (const float4*)We2, (unsigned short*)w2,
      (const float4*)Wn1, (unsigned short*)wn1,
      (const float4*)Wn2, (unsigned short*)wn2,
      (const float4*)Wp, (unsigned short*)wp,
      (intx4*)bcnt_e);

  k_bucket<<<(NI_N / 4 + 255) / 256, 256, 0, stream>>>(fg, res, bcnt_e, bcnt_h,
                                                       pairs_e, pairs_h);

  k_edge_fused<<<NBUCK_E, 256, 0, stream>>>(xh_bf, attr_bf, pairs_e, bcnt_e,
                                            w1, be1, w2, be2, edge_msg);
  k_node_fused<<<NBUCK_H, 256, 0, stream>>>(edge_msg, (const short*)xh_bf,
                                            pairs_h, bcnt_h,
                                            wp, bp, wn1, bn1, wn2, bn2,
                                            gamma, beta, out);
}